// Round 5
// baseline (320.787 us; speedup 1.0000x reference)
//
#include <hip/hip_runtime.h>

#define B_SZ   32
#define LEN    2048
#define DIM    256
#define NST    64
#define OUTD   256
#define CHUNK  64
#define NCHUNK (LEN / CHUNK)     // 32
#define ROWS   (B_SZ * LEN)      // 65536

// ws layout (float offsets)
#define OFF_AT   0               // A_tilde [64][64] (row-major)
#define OFF_A64  4096            // A_tilde^64 [64][64]
#define OFF_MI   8192            // Minv [n][m], [64][64]
#define OFF_S    12288           // chunk states [B][NCHUNK][64]; carry rewrites in place
#define OFF_U    77824           // u = dt * v @ Minv^T  [ROWS][64]
#define OFF_H    4272128         // h states [ROWS][64]; v aliases H (v dead before chunk2)
#define OFF_V    OFF_H
#define WS_FLOATS (OFF_H + (size_t)ROWS * 64)   // 8,466,432 floats = 33.9 MiB

// ---------------------------------------------------------------------------
// Dot-form GEMM tile: out[r][c] = sum_k xs[r][k] * bs[c][k]
// xs: [128][68] natural (pad 68, b128-aligned rows; reads are 4-distinct-addr
//     wave broadcasts -> conflict-free).
// bs: [64][64] with XOR block swizzle: element (m, k) lives at
//     m*64 + 4*((k>>2) ^ (m&15)) + (k&3). Both stores (from coalesced global
//     float4) and reads are full b128; reads are 4-addr broadcasts.
// Thread t: rows tg+16i (tg = t>>4, i=0..7), cols c0..c0+3 (c0 = 4*(t&15)).
// 12 LDS instr per 128 FMA -> VALU-bound.
// ---------------------------------------------------------------------------
__device__ __forceinline__ void accum64(const float* __restrict__ xs,
                                        const float* __restrict__ bs,
                                        int tg, int c0, float acc[8][4]) {
#pragma unroll
  for (int kb = 0; kb < 16; ++kb) {
    float xv[8][4];
#pragma unroll
    for (int i = 0; i < 8; ++i)
      *(float4*)xv[i] = *(const float4*)(xs + (tg + 16 * i) * 68 + 4 * kb);
    float bv[4][4];
#pragma unroll
    for (int j = 0; j < 4; ++j) {
      int m = c0 + j;
      *(float4*)bv[j] = *(const float4*)(bs + m * 64 + 4 * (kb ^ (m & 15)));
    }
#pragma unroll
    for (int i = 0; i < 8; ++i)
#pragma unroll
      for (int j = 0; j < 4; ++j) {
        acc[i][j] = fmaf(xv[i][0], bv[j][0], acc[i][j]);
        acc[i][j] = fmaf(xv[i][1], bv[j][1], acc[i][j]);
        acc[i][j] = fmaf(xv[i][2], bv[j][2], acc[i][j]);
        acc[i][j] = fmaf(xv[i][3], bv[j][3], acc[i][j]);
      }
  }
}

// stage 128x64 X tile (pad 68) from global row-major (ldg), cols col0..+63
__device__ __forceinline__ void stage_x(float* __restrict__ xs,
                                        const float* __restrict__ g,
                                        size_t rowbase, int ldg, int col0,
                                        int t) {
#pragma unroll
  for (int i = 0; i < 8; ++i) {
    int e = 4 * (t + 256 * i);               // 0..8188
    int rr = e >> 6, dd = e & 63;
    *(float4*)(xs + rr * 68 + dd) =
        *(const float4*)(g + (rowbase + rr) * (size_t)ldg + col0 + dd);
  }
}

// stage 64x64 W tile (XOR swizzle) from global row-major (ldb), rows row0..,
// cols col0..+63
__device__ __forceinline__ void stage_b(float* __restrict__ bs,
                                        const float* __restrict__ g,
                                        int row0, int ldb, int col0, int t) {
#pragma unroll
  for (int i = 0; i < 4; ++i) {
    int e = 4 * (t + 256 * i);               // 0..4092
    int m = e >> 6, dd = e & 63;
    float4 v = *(const float4*)(g + (size_t)(row0 + m) * ldb + col0 + dd);
    *(float4*)(bs + m * 64 + 4 * ((dd >> 2) ^ (m & 15))) = v;
  }
}

// ---------------------------------------------------------------------------
// K_A fused: block 0 = prep (GJ inverse, 1 barrier/iter; writes Minv, At,
// A64 = At^64 via 6 b128 squarings). Blocks 1..512 = v = x @ B^T (K=256).
// ---------------------------------------------------------------------------
__global__ __launch_bounds__(256) void k_fused0(const float* __restrict__ A,
                                                const float* __restrict__ Bm,
                                                const float* __restrict__ x,
                                                float* __restrict__ ws) {
  __shared__ __align__(16) float sh[12800];   // 51.2 KB
  const int t = threadIdx.x;

  if (blockIdx.x == 0) {
    float* Pa  = sh;            // [64][68]
    float* Pb  = sh + 4352;     // [64][68]
    float* rbM = sh + 8704;     // [2][64]
    float* rbI = sh + 8832;     // [2][64]
    float* cb  = sh + 8960;     // [2][64]

    const int tc = t & 63;      // column owned
    const int tr = t >> 6;      // 0..3; rows 16*tr+i
    float M[16], Iv[16];
    for (int i = 0; i < 16; ++i) {
      int r = 16 * tr + i;
      M[i] = 0.05f * A[r * 64 + tc] + (r == tc ? 1.0f : 0.0f);
      Iv[i] = (r == tc) ? 1.0f : 0.0f;
    }
    if (tr == 0) { rbM[tc] = M[0]; rbI[tc] = Iv[0]; }
    if (tc == 0)
      for (int i = 0; i < 16; ++i) cb[16 * tr + i] = M[i];
    __syncthreads();

    // Gauss-Jordan, no pivoting (M = 1.15I + 0.05*U(0,1): diagonally dominant)
#pragma unroll
    for (int k = 0; k < 64; ++k) {
      const int cur = (k & 1) * 64, nxt = ((k + 1) & 1) * 64;
      float rinv = 1.0f / rbM[cur + k];
      float rM = rbM[cur + tc] * rinv;
      float rI = rbI[cur + tc] * rinv;
#pragma unroll
      for (int i = 0; i < 16; ++i) {
        int r = 16 * tr + i;
        if (r == k) { M[i] = rM; Iv[i] = rI; }
        else {
          float f = cb[cur + r];
          M[i] = fmaf(-f, rM, M[i]);
          Iv[i] = fmaf(-f, rI, Iv[i]);
        }
      }
      if (k < 63) {
        if (tr == ((k + 1) >> 4)) {
          rbM[nxt + tc] = M[(k + 1) & 15];
          rbI[nxt + tc] = Iv[(k + 1) & 15];
        }
        if (tc == k + 1)
          for (int i = 0; i < 16; ++i) cb[nxt + 16 * tr + i] = M[i];
      }
      __syncthreads();
    }

    // Minv and At = 2*Minv - I to global (natural layouts); Pa = At
    for (int i = 0; i < 16; ++i) {
      int r = 16 * tr + i;
      float at = 2.0f * Iv[i] - (r == tc ? 1.0f : 0.0f);
      ws[OFF_MI + r * 64 + tc] = Iv[i];
      ws[OFF_AT + r * 64 + tc] = at;
      Pa[r * 68 + tc] = at;
    }
    __syncthreads();

    // 6 squarings -> A64, all-b128 inner loop
    float* src = Pa; float* dst = Pb;
    const int r0 = 4 * (t >> 4), c0 = 4 * (t & 15);
    for (int it = 0; it < 6; ++it) {
      float acc[4][4] = {};
#pragma unroll
      for (int kb = 0; kb < 16; ++kb) {
        float av[4][4], bv[4][4];
#pragma unroll
        for (int i = 0; i < 4; ++i)
          *(float4*)av[i] = *(const float4*)(src + (r0 + i) * 68 + 4 * kb);
#pragma unroll
        for (int j2 = 0; j2 < 4; ++j2)
          *(float4*)bv[j2] = *(const float4*)(src + (4 * kb + j2) * 68 + c0);
#pragma unroll
        for (int i = 0; i < 4; ++i)
#pragma unroll
          for (int j = 0; j < 4; ++j) {
            acc[i][j] = fmaf(av[i][0], bv[0][j], acc[i][j]);
            acc[i][j] = fmaf(av[i][1], bv[1][j], acc[i][j]);
            acc[i][j] = fmaf(av[i][2], bv[2][j], acc[i][j]);
            acc[i][j] = fmaf(av[i][3], bv[3][j], acc[i][j]);
          }
      }
      __syncthreads();
      for (int i = 0; i < 4; ++i)
        *(float4*)(dst + (r0 + i) * 68 + c0) =
            make_float4(acc[i][0], acc[i][1], acc[i][2], acc[i][3]);
      __syncthreads();
      float* tmp = src; src = dst; dst = tmp;
    }
    for (int i = 0; i < 4; ++i) {
      int f = 4 * (t + 256 * i);
      int r = f >> 6, c = f & 63;
      *(float4*)(ws + OFF_A64 + f) = *(const float4*)(src + r * 68 + c);
    }
  } else {
    // v[r][m] = sum_d x[r][d] * B[m][d]
    float* xs = sh;             // 8704
    float* bs = sh + 8704;      // 4096
    const size_t rowbase = (size_t)(blockIdx.x - 1) * 128;
    const int tg = t >> 4, c0 = 4 * (t & 15);
    float acc[8][4] = {};
    for (int rd = 0; rd < 4; ++rd) {
      stage_x(xs, x, rowbase, DIM, rd * 64, t);
      stage_b(bs, Bm, 0, DIM, rd * 64, t);
      __syncthreads();
      accum64(xs, bs, tg, c0, acc);
      __syncthreads();
    }
    float* v = ws + OFF_V;
    for (int i = 0; i < 8; ++i)
      *(float4*)(v + (rowbase + tg + 16 * i) * 64 + c0) =
          make_float4(acc[i][0], acc[i][1], acc[i][2], acc[i][3]);
  }
}

// ---------------------------------------------------------------------------
// K2: u[r][n] = dt * sum_m v[r][m] * Minv[n][m]   (K=64)
// ---------------------------------------------------------------------------
__global__ __launch_bounds__(256) void k_umm(float* __restrict__ ws) {
  __shared__ __align__(16) float sh[12800];
  float* xs = sh;
  float* bs = sh + 8704;
  const int t = threadIdx.x;
  const size_t rowbase = (size_t)blockIdx.x * 128;
  const int tg = t >> 4, c0 = 4 * (t & 15);
  stage_x(xs, ws + OFF_V, rowbase, 64, 0, t);
  stage_b(bs, ws + OFF_MI, 0, 64, 0, t);
  __syncthreads();
  float acc[8][4] = {};
  accum64(xs, bs, tg, c0, acc);
  float* u = ws + OFF_U;
  for (int i = 0; i < 8; ++i)
    *(float4*)(u + (rowbase + tg + 16 * i) * 64 + c0) =
        make_float4(0.1f * acc[i][0], 0.1f * acc[i][1], 0.1f * acc[i][2],
                    0.1f * acc[i][3]);
}

// ---------------------------------------------------------------------------
// Wave-level scan machinery: lane r holds row r of the matrix in 64 VGPRs;
// h broadcast via wave-private LDS (write h[r], read 16 wave-uniform b128s).
// No barriers, no readlane hazards.
// ---------------------------------------------------------------------------
__device__ __forceinline__ void load_arow(const float* __restrict__ M, int r,
                                          float areg[64]) {
#pragma unroll
  for (int i = 0; i < 16; ++i)
    *(float4*)(areg + 4 * i) = *(const float4*)(M + r * 64 + 4 * i);
}

// ---------------------------------------------------------------------------
// K3/K5: chunk scan; each wave processes TWO chunks (ca, ca+16) for ILP.
// phase=1: h0=0, emit final states to S. phase=2: h0=carry-in from S, emit H.
// ---------------------------------------------------------------------------
__global__ __launch_bounds__(256) void k_chunk(float* __restrict__ ws, int phase) {
  __shared__ __align__(16) float hlds[4][2][64];
  const int t = threadIdx.x;
  const int r = t & 63, wid = t >> 6;
  const int b = blockIdx.y;
  const int ca = blockIdx.x * 4 + wid;       // 0..15
  const int cb = ca + 16;                    // 16..31
  float areg[64];
  load_arow(ws + OFF_AT, r, areg);
  const float* ua = ws + OFF_U + (size_t)(b * LEN + ca * CHUNK) * 64;
  const float* ub = ws + OFF_U + (size_t)(b * LEN + cb * CHUNK) * 64;
  float* Ha = ws + OFF_H + (size_t)(b * LEN + ca * CHUNK) * 64;
  float* Hb = ws + OFF_H + (size_t)(b * LEN + cb * CHUNK) * 64;
  float ha = 0.f, hb = 0.f;
  if (phase == 2) {
    if (ca > 0) ha = ws[OFF_S + (b * NCHUNK + ca - 1) * 64 + r];
    hb = ws[OFF_S + (b * NCHUNK + cb - 1) * 64 + r];
  }
  float uca = ua[r], ucb = ub[r];
#pragma unroll 1
  for (int st = 0; st < CHUNK; ++st) {
    float una = (st + 1 < CHUNK) ? ua[(st + 1) * 64 + r] : 0.f;
    float unb = (st + 1 < CHUNK) ? ub[(st + 1) * 64 + r] : 0.f;
    hlds[wid][0][r] = ha;
    hlds[wid][1][r] = hb;
    float a0 = 0.f, a1 = 0.f, a2 = 0.f, a3 = 0.f;
    float b0 = 0.f, b1 = 0.f, b2 = 0.f, b3 = 0.f;
#pragma unroll
    for (int mb = 0; mb < 16; ++mb) {
      float4 hva = *(const float4*)&hlds[wid][0][4 * mb];
      float4 hvb = *(const float4*)&hlds[wid][1][4 * mb];
      a0 = fmaf(areg[4 * mb + 0], hva.x, a0);
      a1 = fmaf(areg[4 * mb + 1], hva.y, a1);
      a2 = fmaf(areg[4 * mb + 2], hva.z, a2);
      a3 = fmaf(areg[4 * mb + 3], hva.w, a3);
      b0 = fmaf(areg[4 * mb + 0], hvb.x, b0);
      b1 = fmaf(areg[4 * mb + 1], hvb.y, b1);
      b2 = fmaf(areg[4 * mb + 2], hvb.z, b2);
      b3 = fmaf(areg[4 * mb + 3], hvb.w, b3);
    }
    ha = (a0 + a1) + (a2 + a3) + uca;
    hb = (b0 + b1) + (b2 + b3) + ucb;
    if (phase == 2) {
      Ha[st * 64 + r] = ha;
      Hb[st * 64 + r] = hb;
    }
    uca = una; ucb = unb;
  }
  if (phase == 1) {
    ws[OFF_S + (b * NCHUNK + ca) * 64 + r] = ha;
    ws[OFF_S + (b * NCHUNK + cb) * 64 + r] = hb;
  }
}

// ---------------------------------------------------------------------------
// K4: carry combine, one wave per batch b, in place on S:
// after: S[b][c-1] = carry-in of chunk c.
// ---------------------------------------------------------------------------
__global__ __launch_bounds__(64) void k_carry(float* __restrict__ ws) {
  __shared__ __align__(16) float hl[64];
  const int r = threadIdx.x;
  const int b = blockIdx.x;
  float areg[64];
  load_arow(ws + OFF_A64, r, areg);
  float* S = ws + OFF_S + b * NCHUNK * 64;
  float h = 0.f;
#pragma unroll 1
  for (int c = 1; c < NCHUNK; ++c) {
    float sv = S[(c - 1) * 64 + r];
    hl[r] = h;
    float a0 = 0.f, a1 = 0.f, a2 = 0.f, a3 = 0.f;
#pragma unroll
    for (int mb = 0; mb < 16; ++mb) {
      float4 hv = *(const float4*)&hl[4 * mb];
      a0 = fmaf(areg[4 * mb + 0], hv.x, a0);
      a1 = fmaf(areg[4 * mb + 1], hv.y, a1);
      a2 = fmaf(areg[4 * mb + 2], hv.z, a2);
      a3 = fmaf(areg[4 * mb + 3], hv.w, a3);
    }
    h = (a0 + a1) + (a2 + a3) + sv;
    S[(c - 1) * 64 + r] = h;
  }
}

// ---------------------------------------------------------------------------
// K6: y[r][o] = sum_n h[r][n] * C[o][n]   (K=64, 4 o-blocks of 64)
// ---------------------------------------------------------------------------
__global__ __launch_bounds__(256) void k_ygemm(const float* __restrict__ Cm,
                                               float* __restrict__ ws,
                                               float* __restrict__ y) {
  __shared__ __align__(16) float sh[12800];
  float* xs = sh;
  float* bs = sh + 8704;
  const int t = threadIdx.x;
  const size_t rowbase = (size_t)blockIdx.x * 128;
  const int tg = t >> 4, c0 = 4 * (t & 15);
  stage_x(xs, ws + OFF_H, rowbase, 64, 0, t);
  for (int ob = 0; ob < 4; ++ob) {
    if (ob > 0) __syncthreads();             // previous accum done reading bs
    stage_b(bs, Cm, ob * 64, 64, 0, t);
    __syncthreads();
    float acc[8][4] = {};
    accum64(xs, bs, tg, c0, acc);
    for (int i = 0; i < 8; ++i)
      *(float4*)(y + (rowbase + tg + 16 * i) * 256 + ob * 64 + c0) =
          make_float4(acc[i][0], acc[i][1], acc[i][2], acc[i][3]);
  }
}

// ---------------------------------------------------------------------------
extern "C" void kernel_launch(void* const* d_in, const int* in_sizes, int n_in,
                              void* d_out, int out_size, void* d_ws,
                              size_t ws_size, hipStream_t stream) {
  const float* x = (const float*)d_in[0];
  const float* A = (const float*)d_in[1];
  const float* Bm = (const float*)d_in[2];
  const float* Cm = (const float*)d_in[3];
  float* y = (float*)d_out;
  float* ws = (float*)d_ws;
  if (ws_size < WS_FLOATS * sizeof(float)) return;

  hipLaunchKernelGGL(k_fused0, dim3(1 + ROWS / 128), dim3(256), 0, stream, A,
                     Bm, x, ws);
  hipLaunchKernelGGL(k_umm, dim3(ROWS / 128), dim3(256), 0, stream, ws);
  hipLaunchKernelGGL(k_chunk, dim3(4, B_SZ), dim3(256), 0, stream, ws, 1);
  hipLaunchKernelGGL(k_carry, dim3(B_SZ), dim3(64), 0, stream, ws);
  hipLaunchKernelGGL(k_chunk, dim3(4, B_SZ), dim3(256), 0, stream, ws, 2);
  hipLaunchKernelGGL(k_ygemm, dim3(ROWS / 128), dim3(256), 0, stream, Cm, ws, y);
}